// Round 2
// baseline (158.293 us; speedup 1.0000x reference)
//
#include <hip/hip_runtime.h>
#include <hip/hip_bf16.h>

// JointLengthLoss: mean over [B,20] of | ||pred_a-pred_b|| - ||gt_a-gt_b|| | / ||gt_a-gt_b||
// B = 524288, joints [B,21,3] f32.
//
// R1: no LDS. Each thread owns one sample and walks the bone chains,
// loading pred+gt joints on demand (12B dwordx3-mergeable loads) and
// accumulating rel-error per bone. Tiny live set -> <=64 VGPR -> high
// occupancy; latency hidden by 8 waves/SIMD instead of LDS staging.

#define FLOATS_PER_SAMPLE 63   // 21 joints * 3

struct F3 { float x, y, z; };

__device__ __forceinline__ F3 ldj(const float* __restrict__ p, int j) {
    F3 r;
    r.x = p[3 * j + 0];
    r.y = p[3 * j + 1];
    r.z = p[3 * j + 2];
    return r;
}

__device__ __forceinline__ float blen(F3 a, F3 b) {
    float dx = a.x - b.x, dy = a.y - b.y, dz = a.z - b.z;
    return sqrtf(dx * dx + dy * dy + dz * dz);
}

__device__ __forceinline__ void acc(float& sum, F3 pa, F3 pb, F3 ga, F3 gb) {
    float pl = blen(pa, pb);
    float gl = blen(ga, gb);
    sum += fabsf(pl - gl) / gl;
}

__global__ __launch_bounds__(256, 8)
void jll_partial_kernel(const float* __restrict__ pred,
                        const float* __restrict__ gt,
                        float* __restrict__ partials) {
    const int tid = threadIdx.x;
    const size_t s = (size_t)blockIdx.x * 256 + tid;
    const float* P = pred + s * FLOATS_PER_SAMPLE;
    const float* G = gt   + s * FLOATS_PER_SAMPLE;

    float sum = 0.0f;
    F3 pa, pb, ga, gb, p20, g20, p0, g0;

    // chain 1: 3 -> 2 -> 20 -> 8 -> 9 -> 10 -> 11
    pa = ldj(P, 3);  ga = ldj(G, 3);
    pb = ldj(P, 2);  gb = ldj(G, 2);  acc(sum, pa, pb, ga, gb);    // (3,2)
    p20 = ldj(P, 20); g20 = ldj(G, 20); acc(sum, pb, p20, gb, g20); // (2,20)
    pa = ldj(P, 8);  ga = ldj(G, 8);  acc(sum, p20, pa, g20, ga);  // (20,8)
    pb = ldj(P, 9);  gb = ldj(G, 9);  acc(sum, pa, pb, ga, gb);    // (8,9)
    pa = ldj(P, 10); ga = ldj(G, 10); acc(sum, pb, pa, gb, ga);    // (9,10)
    pb = ldj(P, 11); gb = ldj(G, 11); acc(sum, pa, pb, ga, gb);    // (10,11)

    // chain 2: 20 -> 4 -> 5 -> 6 -> 7
    pa = ldj(P, 4);  ga = ldj(G, 4);  acc(sum, p20, pa, g20, ga);  // (20,4)
    pb = ldj(P, 5);  gb = ldj(G, 5);  acc(sum, pa, pb, ga, gb);    // (4,5)
    pa = ldj(P, 6);  ga = ldj(G, 6);  acc(sum, pb, pa, gb, ga);    // (5,6)
    pb = ldj(P, 7);  gb = ldj(G, 7);  acc(sum, pa, pb, ga, gb);    // (6,7)

    // chain 3: 20 -> 1 -> 0 -> 16 -> 17 -> 18 -> 19
    pa = ldj(P, 1);  ga = ldj(G, 1);  acc(sum, p20, pa, g20, ga);  // (20,1)
    p0 = ldj(P, 0);  g0 = ldj(G, 0);  acc(sum, pa, p0, ga, g0);    // (1,0)
    pa = ldj(P, 16); ga = ldj(G, 16); acc(sum, p0, pa, g0, ga);    // (0,16)
    pb = ldj(P, 17); gb = ldj(G, 17); acc(sum, pa, pb, ga, gb);    // (16,17)
    pa = ldj(P, 18); ga = ldj(G, 18); acc(sum, pb, pa, gb, ga);    // (17,18)
    pb = ldj(P, 19); gb = ldj(G, 19); acc(sum, pa, pb, ga, gb);    // (18,19)

    // chain 4: 0 -> 12 -> 13 -> 14 -> 15
    pa = ldj(P, 12); ga = ldj(G, 12); acc(sum, p0, pa, g0, ga);    // (0,12)
    pb = ldj(P, 13); gb = ldj(G, 13); acc(sum, pa, pb, ga, gb);    // (12,13)
    pa = ldj(P, 14); ga = ldj(G, 14); acc(sum, pb, pa, gb, ga);    // (13,14)
    pb = ldj(P, 15); gb = ldj(G, 15); acc(sum, pa, pb, ga, gb);    // (14,15)

    // ---- wave64 shuffle reduction, then cross-wave via LDS ----
    #pragma unroll
    for (int off = 32; off > 0; off >>= 1)
        sum += __shfl_down(sum, off);

    __shared__ float wsum[4];
    const int lane = tid & 63;
    const int wid  = tid >> 6;
    if (lane == 0) wsum[wid] = sum;
    __syncthreads();
    if (tid == 0)
        partials[blockIdx.x] = wsum[0] + wsum[1] + wsum[2] + wsum[3];
}

__global__ __launch_bounds__(256)
void jll_final_kernel(const float* __restrict__ partials, int nparts,
                      float* __restrict__ out, float inv_count) {
    const int tid = threadIdx.x;
    float sum = 0.0f;
    for (int i = tid; i < nparts; i += 256) sum += partials[i];

    #pragma unroll
    for (int off = 32; off > 0; off >>= 1)
        sum += __shfl_down(sum, off);

    __shared__ float wsum[4];
    const int lane = tid & 63;
    const int wid  = tid >> 6;
    if (lane == 0) wsum[wid] = sum;
    __syncthreads();
    if (tid == 0)
        out[0] = (wsum[0] + wsum[1] + wsum[2] + wsum[3]) * inv_count;
}

extern "C" void kernel_launch(void* const* d_in, const int* in_sizes, int n_in,
                              void* d_out, int out_size, void* d_ws, size_t ws_size,
                              hipStream_t stream) {
    const float* pred = (const float*)d_in[0];
    const float* gt   = (const float*)d_in[1];
    float* out = (float*)d_out;
    float* partials = (float*)d_ws;

    const int nsamples = in_sizes[0] / FLOATS_PER_SAMPLE;   // 524288
    const int nblocks  = nsamples / 256;                    // 2048 (exact)

    jll_partial_kernel<<<nblocks, 256, 0, stream>>>(pred, gt, partials);

    const float inv_count = 1.0f / ((float)nsamples * 20.0f);
    jll_final_kernel<<<1, 256, 0, stream>>>(partials, nblocks, out, inv_count);
}

// Round 3
// 82.264 us; speedup vs baseline: 1.9242x; 1.9242x over previous
//
#include <hip/hip_runtime.h>
#include <hip/hip_bf16.h>

// JointLengthLoss: mean over [B,20] of | ||pred_a-pred_b|| - ||gt_a-gt_b|| | / ||gt_a-gt_b||
// B = 524288, joints [B,21,3] f32.
//
// R2: per-thread sample, but burst-load the whole 63-float sample (contiguous,
// compiler merges to dwordx3/x4) BEFORE computing -> each 128B line is touched
// by adjacent instrs in adjacent lanes -> no cache-thrash over-fetch (R1 fetched
// 2x input). No LDS staging, no barriers; occupancy capped only by VGPRs
// (launch_bounds(256,4) -> <=128 VGPR -> 4 waves/SIMD).

#define FPS 63   // 21 joints * 3

// constexpr (NOT __constant__ memory) so bone indices fold at compile time.
static constexpr int BA[20] = {3,2,20,8,9,10,20,4,5,6,20,1,0,16,17,18,0,12,13,14};
static constexpr int BB[20] = {2,20,8,9,10,11,4,5,6,7,1,0,16,17,18,19,12,13,14,15};

__global__ __launch_bounds__(256, 4)
void jll_partial_kernel(const float* __restrict__ pred,
                        const float* __restrict__ gt,
                        float* __restrict__ partials) {
    const int tid = threadIdx.x;
    const size_t s = (size_t)blockIdx.x * 256 + tid;
    const float* __restrict__ P = pred + s * FPS;
    const float* __restrict__ G = gt   + s * FPS;

    float j[FPS];   // fully static-indexed after unroll -> registers

    // ---- burst-load pred sample ----
    #pragma unroll
    for (int f = 0; f < FPS; ++f) j[f] = P[f];

    // ---- pred bone lengths ----
    float pl[20];
    #pragma unroll
    for (int b = 0; b < 20; ++b) {
        const int a3 = 3 * BA[b], c3 = 3 * BB[b];
        float dx = j[a3 + 0] - j[c3 + 0];
        float dy = j[a3 + 1] - j[c3 + 1];
        float dz = j[a3 + 2] - j[c3 + 2];
        pl[b] = sqrtf(dx * dx + dy * dy + dz * dz);
    }

    // ---- burst-load gt sample (reuses j registers) ----
    #pragma unroll
    for (int f = 0; f < FPS; ++f) j[f] = G[f];

    // ---- gt lengths + relative error ----
    float sum = 0.0f;
    #pragma unroll
    for (int b = 0; b < 20; ++b) {
        const int a3 = 3 * BA[b], c3 = 3 * BB[b];
        float dx = j[a3 + 0] - j[c3 + 0];
        float dy = j[a3 + 1] - j[c3 + 1];
        float dz = j[a3 + 2] - j[c3 + 2];
        float gl = sqrtf(dx * dx + dy * dy + dz * dz);
        sum += fabsf(pl[b] - gl) / gl;
    }

    // ---- wave64 shuffle reduction, then cross-wave via LDS ----
    #pragma unroll
    for (int off = 32; off > 0; off >>= 1)
        sum += __shfl_down(sum, off);

    __shared__ float wsum[4];
    const int lane = tid & 63;
    const int wid  = tid >> 6;
    if (lane == 0) wsum[wid] = sum;
    __syncthreads();
    if (tid == 0)
        partials[blockIdx.x] = wsum[0] + wsum[1] + wsum[2] + wsum[3];
}

__global__ __launch_bounds__(256)
void jll_final_kernel(const float* __restrict__ partials, int nparts,
                      float* __restrict__ out, float inv_count) {
    const int tid = threadIdx.x;
    float sum = 0.0f;
    for (int i = tid; i < nparts; i += 256) sum += partials[i];

    #pragma unroll
    for (int off = 32; off > 0; off >>= 1)
        sum += __shfl_down(sum, off);

    __shared__ float wsum[4];
    const int lane = tid & 63;
    const int wid  = tid >> 6;
    if (lane == 0) wsum[wid] = sum;
    __syncthreads();
    if (tid == 0)
        out[0] = (wsum[0] + wsum[1] + wsum[2] + wsum[3]) * inv_count;
}

extern "C" void kernel_launch(void* const* d_in, const int* in_sizes, int n_in,
                              void* d_out, int out_size, void* d_ws, size_t ws_size,
                              hipStream_t stream) {
    const float* pred = (const float*)d_in[0];
    const float* gt   = (const float*)d_in[1];
    float* out = (float*)d_out;
    float* partials = (float*)d_ws;

    const int nsamples = in_sizes[0] / FPS;     // 524288
    const int nblocks  = nsamples / 256;        // 2048 (exact)

    jll_partial_kernel<<<nblocks, 256, 0, stream>>>(pred, gt, partials);

    const float inv_count = 1.0f / ((float)nsamples * 20.0f);
    jll_final_kernel<<<1, 256, 0, stream>>>(partials, nblocks, out, inv_count);
}